// Round 1
// baseline (627.812 us; speedup 1.0000x reference)
//
#include <hip/hip_runtime.h>

// ChannelPair2D: out[p, k] = x[p, II[k]] * x[p, JJ[k]] for k over triu(C=64, k=1)
// pairs in row-major order. P = 16*64*64 = 65536 pixels, NPAIR = 2016.
// Memory-bound: 16 MB read + 504 MB write. One thread per output float4.

constexpr int C     = 64;
constexpr int NPAIR = C * (C - 1) / 2;  // 2016
constexpr int NP4   = NPAIR / 4;        // 504 float4 per pixel

__global__ __launch_bounds__(256)
void channel_pair_kernel(const float* __restrict__ x,
                         float4* __restrict__ out,
                         int total_v) {
    int v = blockIdx.x * 256 + threadIdx.x;
    if (v >= total_v) return;

    int pixel = v / NP4;            // magic-mul division (compiler)
    int q     = v - pixel * NP4;
    int k     = q << 2;             // first of 4 consecutive pair indices

    // Row offsets: S(i) = i*(127-i)/2 (always even product -> exact).
    // i = largest row with S(i) <= k; seed from quadratic root, then exact fixup.
    float disc = 16129.0f - 8.0f * (float)k;     // 127^2 - 8k, exact in fp32
    int i = (int)((127.0f - sqrtf(disc)) * 0.5f);
    if (i < 0) i = 0;
    if (i > C - 2) i = C - 2;
    while (i > 0 && (i * (127 - i)) / 2 > k) --i;
    while (((i + 1) * (126 - i)) / 2 <= k) ++i;
    int j = i + 1 + (k - (i * (127 - i)) / 2);

    const float* px = x + pixel * C;   // 256-byte window, L1-resident
    float xi = px[i];
    float4 r;
    r.x = xi * px[j]; ++j;
    if (j == C) { ++i; xi = px[i]; j = i + 1; }
    r.y = xi * px[j]; ++j;
    if (j == C) { ++i; xi = px[i]; j = i + 1; }
    r.z = xi * px[j]; ++j;
    if (j == C) { ++i; xi = px[i]; j = i + 1; }
    r.w = xi * px[j];

    out[v] = r;   // coalesced global_store_dwordx4
}

extern "C" void kernel_launch(void* const* d_in, const int* in_sizes, int n_in,
                              void* d_out, int out_size, void* d_ws, size_t ws_size,
                              hipStream_t stream) {
    const float* x  = (const float*)d_in[0];
    float4* out     = (float4*)d_out;
    int total_v     = out_size / 4;                 // 33,030,144 float4s
    int blocks      = (total_v + 255) / 256;        // exactly 129,024
    channel_pair_kernel<<<blocks, 256, 0, stream>>>(x, out, total_v);
}